// Round 5
// baseline (96.618 us; speedup 1.0000x reference)
//
#include <hip/hip_runtime.h>

namespace {
constexpr int N = 1024;
constexpr int D = 128;
constexpr int E = 32768;
constexpr int TILE = 4;      // nodes per fused block -> grid = 256

typedef __attribute__((address_space(1))) unsigned int gu32;
typedef __attribute__((address_space(3))) unsigned int lu32;

__device__ __forceinline__ void gload_lds16(const float* g, float* l){
  // async global->LDS, 16B per lane, LDS dest = base + lane*16 (linear)
  __builtin_amdgcn_global_load_lds((const gu32*)g, (lu32*)l, 16, 0, 0);
}

// ---- one-block edge build: counts+deg (LDS atomics), shfl scan, bucket fill ----
__global__ __launch_bounds__(1024) void k_edges(const int* __restrict__ ei,
    int* __restrict__ off, int* __restrict__ deg, int* __restrict__ bucket){
  __shared__ int scnt[N], sdeg[N], scur[N];
  __shared__ int wsum[16];
  int t = threadIdx.x;
  scnt[t] = 0; sdeg[t] = 0;
  __syncthreads();
  #pragma unroll
  for(int it = 0; it < E/1024; ++it){
    int e = it*1024 + t;
    int s = ei[e], d = ei[E+e];
    atomicAdd(&scnt[d], 1);
    atomicAdd(&sdeg[s], 1);
    atomicAdd(&sdeg[d], 1);
  }
  __syncthreads();
  deg[t] = sdeg[t];
  int v = scnt[t], own = v;
  int lane = t & 63, w = t >> 6;
  #pragma unroll
  for(int o2 = 1; o2 < 64; o2 <<= 1){
    int nb = __shfl_up(v, o2, 64);
    if(lane >= o2) v += nb;
  }
  if(lane == 63) wsum[w] = v;
  __syncthreads();
  int pref = 0;
  #pragma unroll
  for(int i = 0; i < 16; ++i){ int sv = wsum[i]; if(i < w) pref += sv; }
  int incl = v + pref, excl = incl - own;
  off[t] = excl; scur[t] = excl;
  if(t == N-1) off[N] = incl;
  __syncthreads();
  #pragma unroll
  for(int it = 0; it < E/1024; ++it){
    int e = it*1024 + t;
    int s = ei[e], d = ei[E+e];
    int p = atomicAdd(&scur[d], 1);
    bucket[p] = s;
  }
}

// ---- fused GEMM chain ----
// 256 blocks x 256 thr. thread = (m = f-pair 0..63, kq = k-quarter 0..3).
// Per thread: 2 features x 4 nodes x 8 k per 32k-chunk; combine k-quarters at
// phase ends via LDS scratch. Weights staged by global_load_lds (16B/lane) into
// linear [128][32] chunks; column XOR-swizzle (pre-swizzled global source +
// swizzled read slot) keeps the 64-distinct-row ds_read_b128 conflict-free.
__global__ __launch_bounds__(256, 3) void k_fused(
    const float* __restrict__ x,
    const float* __restrict__ Wl, const float* __restrict__ bl,
    const float* __restrict__ Wr,
    const float* __restrict__ W1, const float* __restrict__ b1,
    const float* __restrict__ W2, const float* __restrict__ b2,
    const float* __restrict__ Wp, const float* __restrict__ Wd,
    const float* __restrict__ bd,
    const int* __restrict__ off, const int* __restrict__ bucket,
    const int* __restrict__ deg,
    float* __restrict__ delta, float* __restrict__ res,
    float* __restrict__ scores, float* __restrict__ s1, float* __restrict__ s2)
{
  __shared__ float sW[2][128*32];
  __shared__ float sx[TILE][D], smean[TILE][D], sxg[TILE][D], sdr[TILE][D];
  __shared__ float cscr[4][64][9];   // k-quarter combine scratch (9-pad: bank-free)
  int t = threadIdx.x;
  int base = blockIdx.x * TILE;
  int lane = t & 63;
  int m = t & 63, kq = t >> 6;
  int f0 = m*2, swz = m & 7;

  const float* WpA = Wp;
  const float* WpC = Wp + 2*D*D;
  const float* WpR = Wp + 3*D*D;

  auto prefetch = [&](int ns, int pbuf){
    int nm = ns >> 2, nkc = ns & 3;
    const float* M = nm==0?Wl: nm==1?Wr: nm==2?WpA: nm==3?WpC: nm==4?WpR: Wd;
    float* dst = sW[pbuf];
    int i0 = kq*4;
    #pragma unroll
    for(int ii = 0; ii < 4; ++ii){
      int inst = i0 + ii;
      int r = inst*8 + (lane>>3);
      int cg = (lane&7) ^ ((r>>1)&7);          // inverse-swizzled source column
      gload_lds16(M + r*D + nkc*32 + cg*4, dst + inst*256);
    }
  };

  prefetch(0, 0);

  // x tile -> LDS
  if(t < 128) *(float4*)&sx[0][t*4] = *(const float4*)&x[base*D + t*4];

  // neighbor mean (f = t&127, node-half = t>>7)
  {
    int f = t & 127, hh = t >> 7;
    #pragma unroll
    for(int p2 = 0; p2 < 2; ++p2){
      int p = p2*2 + hh;
      int n = base + p, beg = off[n], end = off[n+1];
      float a0=0.f, a1=0.f, a2=0.f, a3=0.f;
      int j = beg;
      for(; j+3 < end; j += 4){
        int i0=bucket[j], i1=bucket[j+1], i2=bucket[j+2], i3=bucket[j+3];
        a0 += x[i0*D+f]; a1 += x[i1*D+f]; a2 += x[i2*D+f]; a3 += x[i3*D+f];
      }
      for(; j < end; ++j) a0 += x[bucket[j]*D+f];
      int c = end - beg;
      smean[p][f] = (a0+a1+a2+a3) / (float)(c>1?c:1);
    }
  }
  __syncthreads();

  float acc[8] = {0,0,0,0,0,0,0,0};  // [ff*4+p]
  float gg[8];                        // gelu values for S1
  int buf = 0;
  for(int s = 0; s < 24; ++s){
    int mm = s >> 2, kc = s & 3;
    if(s < 23) prefetch(s+1, buf^1);
    const float (*sIn)[D] = (mm==0)?smean:(mm==1)?sx:(mm<5)?sxg:sdr;
    const float* wb = sW[buf];
    #pragma unroll
    for(int k4 = 0; k4 < 2; ++k4){
      int slot = (kq*2 + k4) ^ swz;            // swizzled read slot
      float4 w0 = *(const float4*)&wb[f0*32 + slot*4];
      float4 w1 = *(const float4*)&wb[f0*32 + 32 + slot*4];
      int kx = kc*32 + kq*8 + k4*4;
      #pragma unroll
      for(int p = 0; p < 4; ++p){
        float4 vv = *(const float4*)&sIn[p][kx];
        acc[p]   += vv.x*w0.x + vv.y*w0.y + vv.z*w0.z + vv.w*w0.w;
        acc[4+p] += vv.x*w1.x + vv.y*w1.y + vv.z*w1.z + vv.w*w1.w;
      }
    }
    if((s & 3) == 3 && s >= 7){
      // combine the 4 k-quarters
      #pragma unroll
      for(int j = 0; j < 8; ++j) cscr[kq][m][j] = acc[j];
      __syncthreads();
      #pragma unroll
      for(int q = 1; q < 4; ++q){
        #pragma unroll
        for(int j = 0; j < 8; ++j) acc[j] += cscr[(kq+q)&3][m][j];
      }
      if(s == 7){                 // gelu(mean@Wl^T + x@Wr^T + bl + x)
        float2 blv = *(const float2*)&bl[f0];
        #pragma unroll
        for(int p = 0; p < 4; ++p){
          float v0 = acc[p]   + blv.x + sx[p][f0];
          float v1 = acc[4+p] + blv.y + sx[p][f0+1];
          float g0 = 0.5f*v0*(1.0f + erff(v0*0.7071067811865475f));
          float g1 = 0.5f*v1*(1.0f + erff(v1*0.7071067811865475f));
          gg[p] = g0; gg[4+p] = g1;
          if(kq == 0){ sxg[p][f0] = g0; sxg[p][f0+1] = g1; }
        }
      } else if(s == 11){         // delta_raw -> sdr
        if(kq == 0){
          #pragma unroll
          for(int p = 0; p < 4; ++p){ sdr[p][f0] = acc[p]; sdr[p][f0+1] = acc[4+p]; }
        }
      } else if(s == 15){         // Cs -> S1/S2
        if(kq == 0){
          float sa=0.f, sb=0.f, sc=0.f, sd=0.f;
          #pragma unroll
          for(int p = 0; p < 4; ++p){
            sa += gg[p]*acc[p]; sb += gg[4+p]*acc[4+p];
            sc += acc[p];       sd += acc[4+p];
          }
          atomicAdd(&s1[f0], sa);   atomicAdd(&s1[f0+1], sb);
          atomicAdd(&s2[f0], sc);   atomicAdd(&s2[f0+1], sd);
        }
      } else if(s == 19){         // residual
        if(kq == 0){
          #pragma unroll
          for(int p = 0; p < 4; ++p){
            float2 rv; rv.x = acc[p]; rv.y = acc[4+p];
            *(float2*)&res[(base+p)*D + f0] = rv;
          }
        }
      } else {                    // s == 23: delta = softplus(. + bd)
        if(kq == 0){
          float2 bdv = *(const float2*)&bd[f0];
          #pragma unroll
          for(int p = 0; p < 4; ++p){
            float d0 = acc[p] + bdv.x, d1 = acc[4+p] + bdv.y;
            float sp0 = (d0 > 20.f) ? d0 : log1pf(expf(d0));
            float sp1 = (d1 > 20.f) ? d1 : log1pf(expf(d1));
            float2 dv; dv.x = sp0; dv.y = sp1;
            *(float2*)&delta[(base+p)*D + f0] = dv;
          }
        }
      }
      #pragma unroll
      for(int j = 0; j < 8; ++j) acc[j] = 0.f;
    }
    __syncthreads();
    buf ^= 1;
  }

  // scores MLP (R=32) + deg
  if(t < 128){
    int r = t & 31, p = t >> 5;
    float h = 0.f;
    #pragma unroll
    for(int k4 = 0; k4 < 32; ++k4){
      float4 w = *(const float4*)&W1[r*D + k4*4];
      float4 g = *(const float4*)&sxg[p][k4*4];
      h += g.x*w.x + g.y*w.y + g.z*w.z + g.w*w.w;
    }
    h += b1[r];
    h = fmaxf(h, 0.f);
    float part = h * W2[r];
    part += __shfl_down(part, 16, 32);
    part += __shfl_down(part, 8, 32);
    part += __shfl_down(part, 4, 32);
    part += __shfl_down(part, 2, 32);
    part += __shfl_down(part, 1, 32);
    if(r == 0) scores[base + p] = part + b2[0] + (float)deg[base + p];
  }
}

__device__ __forceinline__ unsigned long long shflx64(unsigned long long v, int mask){
  int lo = __shfl_xor((int)(v & 0xffffffffull), mask);
  int hi = __shfl_xor((int)(v >> 32), mask);
  return ((unsigned long long)(unsigned int)hi << 32) | (unsigned int)lo;
}

// ---- hybrid bitonic argsort: j>=64 via LDS+barrier, j<=32 in-register shfl ----
__global__ __launch_bounds__(1024) void k_sort(const float* __restrict__ scores, int* sidx){
  __shared__ unsigned long long keys[N];
  int t = threadIdx.x;
  unsigned int u = __float_as_uint(scores[t]);
  u = (u >> 31) ? ~u : (u | 0x80000000u);    // monotone float->uint (ascending)
  unsigned int ks = ~u;                       // descending score
  keys[t] = ((unsigned long long)ks << 32) | (unsigned int)t;
  __syncthreads();
  for(int k = 2; k <= N; k <<= 1){
    for(int j = k >> 1; j >= 64; j >>= 1){
      int ixj = t ^ j;
      if(ixj > t){
        bool up = ((t & k) == 0);
        unsigned long long a = keys[t], b = keys[ixj];
        if((a > b) == up){ keys[t] = b; keys[ixj] = a; }
      }
      __syncthreads();
    }
    unsigned long long kv = keys[t];
    bool up = ((t & k) == 0);
    for(int j = ((k>>1) < 32 ? (k>>1) : 32); j >= 1; j >>= 1){
      unsigned long long pv = shflx64(kv, j);
      bool lower = ((t & j) == 0);
      unsigned long long mn = kv < pv ? kv : pv;
      unsigned long long mx = kv < pv ? pv : kv;
      kv = (lower == up) ? mn : mx;
    }
    keys[t] = kv;
    __syncthreads();
  }
  sidx[t] = (int)(keys[t] & 0xFFFFFFFFu);
}

// ---- per-head inclusive cumsum over sorted order (wave shuffle scan) ----
__global__ __launch_bounds__(1024) void k_cumsum(const float* __restrict__ delta,
     const int* __restrict__ sidx, const float* __restrict__ Bp, float* __restrict__ pfxT){
  int h = blockIdx.x, t = threadIdx.x;
  float v = delta[sidx[t]*D + h] * Bp[h];
  int lane = t & 63, w = t >> 6;
  #pragma unroll
  for(int o2 = 1; o2 < 64; o2 <<= 1){
    float nb = __shfl_up(v, o2, 64);
    if(lane >= o2) v += nb;
  }
  __shared__ float wsum[16];
  if(lane == 63) wsum[w] = v;
  __syncthreads();
  float pref = 0.f;
  #pragma unroll
  for(int i = 0; i < 16; ++i){
    float s = wsum[i];
    if(i < w) pref += s;
  }
  pfxT[h*N + t] = v + pref;   // coalesced write
}

// ---- final: y + res*Dp, LayerNorm over D, un-permute, add x ----
__global__ __launch_bounds__(128) void k_final(
    const float* __restrict__ delta, const float* __restrict__ res,
    const float* __restrict__ pfxT, const int* __restrict__ sidx,
    const float* __restrict__ s1, const float* __restrict__ s2,
    const float* __restrict__ A, const float* __restrict__ Bp,
    const float* __restrict__ Dp, const float* __restrict__ x,
    float* __restrict__ out){
  int l = blockIdx.x, h = threadIdx.x;
  int i = sidx[l];
  float dlt = delta[i*D + h];
  float dAv = expf(dlt * A[h]) * Bp[h];
  float o = dAv * s1[h] + pfxT[h*N + l] * s2[h] + res[i*D + h] * Dp[0];
  __shared__ float sm1[2], sm2[2];
  float v = o;
  v += __shfl_down(v, 32); v += __shfl_down(v, 16); v += __shfl_down(v, 8);
  v += __shfl_down(v, 4);  v += __shfl_down(v, 2);  v += __shfl_down(v, 1);
  int wid = h >> 6, lane = h & 63;
  if(lane == 0) sm1[wid] = v;
  __syncthreads();
  float mean = (sm1[0] + sm1[1]) * (1.0f/(float)D);
  float cdev = o - mean;
  float cv = cdev * cdev;
  cv += __shfl_down(cv, 32); cv += __shfl_down(cv, 16); cv += __shfl_down(cv, 8);
  cv += __shfl_down(cv, 4);  cv += __shfl_down(cv, 2);  cv += __shfl_down(cv, 1);
  if(lane == 0) sm2[wid] = cv;
  __syncthreads();
  float var = (sm2[0] + sm2[1]) * (1.0f/(float)D);
  float nrm = cdev * rsqrtf(var + 1e-5f);
  out[i*D + h] = x[i*D + h] + nrm;
}

} // namespace

extern "C" void kernel_launch(void* const* d_in, const int* in_sizes, int n_in,
                              void* d_out, int out_size, void* d_ws, size_t ws_size,
                              hipStream_t stream){
  const float* x   = (const float*)d_in[0];
  const int*   ei  = (const int*)d_in[1];
  const float* Wl  = (const float*)d_in[2];
  const float* bl  = (const float*)d_in[3];
  const float* Wr  = (const float*)d_in[4];
  const float* W1  = (const float*)d_in[5];
  const float* b1  = (const float*)d_in[6];
  const float* W2  = (const float*)d_in[7];
  const float* b2  = (const float*)d_in[8];
  const float* Wp  = (const float*)d_in[9];
  const float* A   = (const float*)d_in[10];
  const float* Bp  = (const float*)d_in[11];
  const float* Dp  = (const float*)d_in[12];
  const float* Wd  = (const float*)d_in[13];
  const float* bd  = (const float*)d_in[14];

  char* ws = (char*)d_ws;
  size_t o = 0;
  auto alloc = [&](size_t bytes)->char*{
    char* p = ws + o;
    o = (o + bytes + 255) & ~(size_t)255;
    return p;
  };
  // zero-initialized region (one memset): S1, S2
  float* s1     = (float*)alloc(D*4);
  float* s2     = (float*)alloc(D*4);
  size_t zbytes = o;
  int*   off    = (int*)  alloc((N+1)*4);
  int*   deg    = (int*)  alloc(N*4);
  int*   bucket = (int*)  alloc(E*4);
  float* scores = (float*)alloc(N*4);
  int*   sidx   = (int*)  alloc(N*4);
  float* delta  = (float*)alloc((size_t)N*D*4);
  float* res    = (float*)alloc((size_t)N*D*4);
  float* pfxT   = (float*)alloc((size_t)N*D*4);
  (void)ws_size; (void)in_sizes; (void)n_in; (void)out_size;

  hipMemsetAsync(d_ws, 0, zbytes, stream);
  k_edges <<<1, 1024, 0, stream>>>(ei, off, deg, bucket);
  k_fused <<<N/TILE, 256, 0, stream>>>(x, Wl, bl, Wr, W1, b1, W2, b2, Wp, Wd, bd,
                                       off, bucket, deg, delta, res, scores, s1, s2);
  k_sort  <<<1, 1024, 0, stream>>>(scores, sidx);
  k_cumsum<<<D, 1024, 0, stream>>>(delta, sidx, Bp, pfxT);
  k_final <<<N, 128, 0, stream>>>(delta, res, pfxT, sidx, s1, s2, A, Bp, Dp, x, (float*)d_out);
}